// Round 3
// baseline (1623.040 us; speedup 1.0000x reference)
//
#include <hip/hip_runtime.h>

#define T_LEN 512
#define F_DIM 6
#define H_DIM 64

typedef _Float16 h2v __attribute__((ext_vector_type(2)));

// --- DPP / swizzle helpers (all ctrl fields are literal via macros) ---
// XOR-walk transition of the packed h pair (int-typed):
#define XSTEP_DPP(ctrl) hpi = __builtin_amdgcn_update_dpp(0, hpi, (ctrl), 0xF, 0xF, false)
#define XSTEP_SWZ(mask) hpi = __builtin_amdgcn_ds_swizzle(hpi, ((mask) << 10) | 0x1F)
// quad_perm [1,0,3,2] = 0xB1 (lane^1), [2,3,0,1] = 0x4E (lane^2)

#define DOT(s)                                                                  \
    {                                                                           \
        h2v hh = __builtin_bit_cast(h2v, hpi);                                  \
        if ((s) & 1) acc1 = __builtin_amdgcn_fdot2(hh, ws[(s)], acc1, false);   \
        else         acc0 = __builtin_amdgcn_fdot2(hh, ws[(s)], acc0, false);   \
    }

// 4 dots with xor1, xor2, xor1 transitions inside, then MID transition
#define QUAD(b, MID)                                                            \
    DOT(b) XSTEP_DPP(0xB1); DOT((b)+1) XSTEP_DPP(0x4E); DOT((b)+2)              \
    XSTEP_DPP(0xB1); DOT((b)+3) MID
#define OCT(b, BIG) QUAD(b, XSTEP_SWZ(4);) QUAD((b)+4, BIG)

// DPP add for wave reduction
#define DPP_ADD(p, ctrl, rmask)                                                 \
    ((p) + __builtin_bit_cast(float, __builtin_amdgcn_update_dpp(                \
               0, __builtin_bit_cast(int, (p)), (ctrl), (rmask), 0xF, false)))

// One ODE sub-step: gather own pair -> 32-step Gray XOR walk with fdot2 -> tanh -> decay mix
#define ODE_STEP do {                                                           \
    int b0 = __builtin_amdgcn_ds_bpermute(a0, __builtin_bit_cast(int, h));      \
    int b1 = __builtin_amdgcn_ds_bpermute(a1, __builtin_bit_cast(int, h));      \
    h2v hpv;                                                                    \
    hpv.x = (_Float16)__builtin_bit_cast(float, b0);                            \
    hpv.y = (_Float16)__builtin_bit_cast(float, b1);                            \
    int hpi = __builtin_bit_cast(int, hpv);                                     \
    float acc0 = 0.f, acc1 = 0.f;                                               \
    OCT(0, XSTEP_SWZ(8);) OCT(8, XSTEP_SWZ(16);)                                \
    OCT(16, XSTEP_SWZ(8);) OCT(24, ;)                                           \
    float z = u + (acc0 + acc1);                                                \
    float e2z = __builtin_amdgcn_exp2f(z * 2.8853900817779268f);                \
    float tn  = fmaf(-2.0f, __builtin_amdgcn_rcpf(1.0f + e2z), 1.0f);           \
    h = fmaf(h, decay, tn * omd);                                               \
} while (0)

__global__ __launch_bounds__(64, 4) void liquid_rnn_kernel(
    const float* __restrict__ x_seq,   // (B,T,F)
    const float* __restrict__ dt_p,    // scalar
    const float* __restrict__ W_in,    // (H,F)
    const float* __restrict__ b_in,    // (H)
    const float* __restrict__ W_rec,   // (H,H)
    const float* __restrict__ b_rec,   // (H)
    const float* __restrict__ tau,     // (H)
    const float* __restrict__ W_cls,   // (1,H)
    const float* __restrict__ b_cls,   // (1)
    const int*   __restrict__ ode_steps_p,
    float* __restrict__ out,           // (B,T,1)
    int B)
{
    const int b = blockIdx.x;
    if (b >= B) return;
    const int j = threadIdx.x;  // lane 0..63, owns h[j]

    const int   ode_steps = ode_steps_p[0];
    const float steps_dt  = dt_p[0] / (float)ode_steps;
    const float decay     = __expf(-steps_dt / fabsf(tau[j]));
    const float omd       = 1.0f - decay;

    // Pre-permuted recurrent weights: at walk step s, lane j holds h-pair
    // index p = (j&31) ^ gray(s); store the matching W_rec pair.
    const int m = j & 31;
    h2v ws[32];
#pragma unroll
    for (int s = 0; s < 32; ++s) {
        int p = m ^ (s ^ (s >> 1));
        h2v w;
        w.x = (_Float16)W_rec[j * H_DIM + 2 * p + 0];
        w.y = (_Float16)W_rec[j * H_DIM + 2 * p + 1];
        ws[s] = w;
    }

    // bpermute byte-addresses for gathering (h[2m], h[2m+1])
    const int a0 = (2 * m) << 2;
    const int a1 = a0 + 4;

    float win[F_DIM];
#pragma unroll
    for (int f = 0; f < F_DIM; ++f) win[f] = W_in[j * F_DIM + f];

    const float bias_u = b_in[j] + b_rec[j];
    const float wc     = W_cls[j];
    const float bc     = b_cls[0];

    float h = 0.0f;
    const float* xrow = x_seq + (size_t)b * T_LEN * F_DIM;
    float* orow = out + (size_t)b * T_LEN;

    // x prefetch registers (one t ahead)
    float xc[F_DIM], xn[F_DIM];
#pragma unroll
    for (int f = 0; f < F_DIM; ++f) xc[f] = xrow[f];

    for (int t = 0; t < T_LEN; ++t) {
        // issue next-t x loads early (clamped index; hidden under ode compute)
        const float* xnx = xrow + (size_t)((t + 1 < T_LEN) ? t + 1 : t) * F_DIM;
#pragma unroll
        for (int f = 0; f < F_DIM; ++f) xn[f] = xnx[f];

        float u = bias_u;
#pragma unroll
        for (int f = 0; f < F_DIM; ++f) u = fmaf(xc[f], win[f], u);

        if (ode_steps == 4) {
            ODE_STEP; ODE_STEP; ODE_STEP; ODE_STEP;
        } else {
            for (int s2 = 0; s2 < ode_steps; ++s2) { ODE_STEP; }
        }

        // classifier: p = sum_j h[j]*wc[j]  via pure-VALU DPP reduction
        float p = h * wc;
        p = DPP_ADD(p, 0x121, 0xF);  // row_ror:1
        p = DPP_ADD(p, 0x122, 0xF);  // row_ror:2
        p = DPP_ADD(p, 0x124, 0xF);  // row_ror:4
        p = DPP_ADD(p, 0x128, 0xF);  // row_ror:8  -> every lane holds its 16-row sum
        p = DPP_ADD(p, 0x142, 0xA);  // row_bcast15 into rows 1,3
        p = DPP_ADD(p, 0x143, 0x8);  // row_bcast31 into row 3 -> lane63 = total
        if (j == 63) orow[t] = p + bc;

#pragma unroll
        for (int f = 0; f < F_DIM; ++f) xc[f] = xn[f];
    }
}

extern "C" void kernel_launch(void* const* d_in, const int* in_sizes, int n_in,
                              void* d_out, int out_size, void* d_ws, size_t ws_size,
                              hipStream_t stream) {
    const float* x_seq = (const float*)d_in[0];
    const float* dt_p  = (const float*)d_in[1];
    const float* W_in  = (const float*)d_in[2];
    const float* b_in  = (const float*)d_in[3];
    const float* W_rec = (const float*)d_in[4];
    const float* b_rec = (const float*)d_in[5];
    const float* tau   = (const float*)d_in[6];
    const float* W_cls = (const float*)d_in[7];
    const float* b_cls = (const float*)d_in[8];
    const int*   ode_s = (const int*)d_in[9];
    float* outp = (float*)d_out;

    const int B = in_sizes[0] / (T_LEN * F_DIM);  // 4096

    liquid_rnn_kernel<<<B, 64, 0, stream>>>(x_seq, dt_p, W_in, b_in, W_rec, b_rec,
                                            tau, W_cls, b_cls, ode_s, outp, B);
}

// Round 4
// 1545.931 us; speedup vs baseline: 1.0499x; 1.0499x over previous
//
#include <hip/hip_runtime.h>

#define T_LEN 512
#define F_DIM 6
#define H_DIM 64
#define BPW   16   // batches per wave (= mfma N dimension)

typedef short  bf16x8 __attribute__((ext_vector_type(8)));
typedef float  f32x4  __attribute__((ext_vector_type(4)));

static __device__ __forceinline__ unsigned short f2bf(float f) {
    unsigned u = __builtin_bit_cast(unsigned, f);
    u += 0x7FFFu + ((u >> 16) & 1u);   // round-to-nearest-even
    return (unsigned short)(u >> 16);
}
static __device__ __forceinline__ float bf2f(unsigned short h) {
    return __builtin_bit_cast(float, ((unsigned)h) << 16);
}

union frag_u { bf16x8 v; int i[4]; unsigned short s[8]; };

// One wave (64 lanes) advances BPW=16 batches through all T*ode_steps.
// h state: hd[rt][r] (f32, D-layout: batch=lane&15, n=rt*16+4*(lane>>4)+r)
//          hb[ks]    (bf16 B-frag: batch=lane&15, k=ks*32+8*(lane>>4)+i)
__global__ __launch_bounds__(64, 1) void liquid_rnn_mfma(
    const float* __restrict__ x_seq, const float* __restrict__ dt_p,
    const float* __restrict__ W_in,  const float* __restrict__ b_in,
    const float* __restrict__ W_rec, const float* __restrict__ b_rec,
    const float* __restrict__ tau,   const float* __restrict__ W_cls,
    const float* __restrict__ b_cls, const int* __restrict__ ode_steps_p,
    float* __restrict__ out, int B)
{
    const int l = threadIdx.x;
    const int c = l & 15;      // batch column
    const int g = l >> 4;      // lane group
    const int b0 = blockIdx.x * BPW;
    if (b0 >= B) return;

    const int   ode_steps = ode_steps_p[0];
    const float steps_dt  = dt_p[0] / (float)ode_steps;
    const float bc        = b_cls[0];

    // per-lane D-row constants: n(rt,r) = rt*16 + 4g + r
    float decay_v[4][4], omd_v[4][4], omd2_v[4][4], wc_v[4][4];
    f32x4 bias_c[4];
#pragma unroll
    for (int rt = 0; rt < 4; ++rt) {
#pragma unroll
        for (int r = 0; r < 4; ++r) {
            const int n = rt * 16 + 4 * g + r;
            const float d = __expf(-steps_dt / fabsf(tau[n]));
            decay_v[rt][r] = d;
            omd_v[rt][r]   = 1.0f - d;
            omd2_v[rt][r]  = 2.0f * (1.0f - d);
            wc_v[rt][r]    = W_cls[n];
            bias_c[rt][r]  = b_in[n] + b_rec[n];
        }
    }

    // W_rec A-frags (hi/lo bf16 split): wa[rt][ks].s[i] = W_rec[rt*16+c][ks*32+8g+i]
    frag_u wa_hi[4][2], wa_lo[4][2];
#pragma unroll
    for (int rt = 0; rt < 4; ++rt)
#pragma unroll
        for (int ks = 0; ks < 2; ++ks)
#pragma unroll
            for (int i = 0; i < 8; ++i) {
                const float w = W_rec[(rt * 16 + c) * H_DIM + ks * 32 + 8 * g + i];
                const unsigned short hh = f2bf(w);
                wa_hi[rt][ks].s[i] = hh;
                wa_lo[rt][ks].s[i] = f2bf(w - bf2f(hh));
            }

    // W_in A-frags, K padded 6->32: valid iff g==0 && i<6
    frag_u wu_hi[4], wu_lo[4];
#pragma unroll
    for (int rt = 0; rt < 4; ++rt)
#pragma unroll
        for (int i = 0; i < 8; ++i) {
            const float w = (g == 0 && i < F_DIM) ? W_in[(rt * 16 + c) * F_DIM + i] : 0.f;
            const unsigned short hh = f2bf(w);
            wu_hi[rt].s[i] = hh;
            wu_lo[rt].s[i] = f2bf(w - bf2f(hh));
        }

    // bpermute source-lane byte addresses (verified index math):
    // dwords 0,1 pull from lane c+16*(2*(g&1)); dwords 2,3 from +16 more
    const int aE = 4 * (c + 16 * (2 * (g & 1)));
    const int aO = aE + 64;
    const bool lohalf = (l < 32);   // rt' = 2ks (+1 for upper half)

    // h state
    f32x4 hd[4];
    frag_u hb[2];
#pragma unroll
    for (int rt = 0; rt < 4; ++rt) hd[rt] = (f32x4){0.f, 0.f, 0.f, 0.f};
    hb[0].i[0] = hb[0].i[1] = hb[0].i[2] = hb[0].i[3] = 0;
    hb[1].i[0] = hb[1].i[1] = hb[1].i[2] = hb[1].i[3] = 0;

    // x stream (lanes g==0 carry batch c's features)
    const float* xr = x_seq + (size_t)(b0 + c) * T_LEN * F_DIM;
    float x0, x1, x2, x3, x4, x5;
    if (g == 0) {
        float2 p0 = *(const float2*)(xr + 0);
        float2 p1 = *(const float2*)(xr + 2);
        float2 p2 = *(const float2*)(xr + 4);
        x0 = p0.x; x1 = p0.y; x2 = p1.x; x3 = p1.y; x4 = p2.x; x5 = p2.y;
    } else { x0 = x1 = x2 = x3 = x4 = x5 = 0.f; }

    for (int t = 0; t < T_LEN; ++t) {
        // build x B-frags (hi/lo)
        frag_u xh, xl;
#define SETX(i, val) { unsigned short hh = f2bf(val); xh.s[i] = hh; xl.s[i] = f2bf((val) - bf2f(hh)); }
        SETX(0, x0) SETX(1, x1) SETX(2, x2) SETX(3, x3) SETX(4, x4) SETX(5, x5)
#undef SETX
        xh.s[6] = xh.s[7] = xl.s[6] = xl.s[7] = 0;

        // prefetch next t (hidden under the ode compute)
        float n0, n1, n2, n3, n4, n5;
        if (g == 0 && t + 1 < T_LEN) {
            const float* xn = xr + (size_t)(t + 1) * F_DIM;
            float2 p0 = *(const float2*)(xn + 0);
            float2 p1 = *(const float2*)(xn + 2);
            float2 p2 = *(const float2*)(xn + 4);
            n0 = p0.x; n1 = p0.y; n2 = p1.x; n3 = p1.y; n4 = p2.x; n5 = p2.y;
        } else { n0 = n1 = n2 = n3 = n4 = n5 = 0.f; }

        // u[rt] = bias + W_in·x   (hi*hi + hi*lo + lo*hi)
        f32x4 u[4];
#pragma unroll
        for (int rt = 0; rt < 4; ++rt) {
            u[rt] = __builtin_amdgcn_mfma_f32_16x16x32_bf16(wu_hi[rt].v, xh.v, bias_c[rt], 0, 0, 0);
            u[rt] = __builtin_amdgcn_mfma_f32_16x16x32_bf16(wu_hi[rt].v, xl.v, u[rt], 0, 0, 0);
            u[rt] = __builtin_amdgcn_mfma_f32_16x16x32_bf16(wu_lo[rt].v, xh.v, u[rt], 0, 0, 0);
        }

        for (int s = 0; s < ode_steps; ++s) {
            // z = u + (W_hi + W_lo)·h   : 16 mfma
            f32x4 acc[4];
#pragma unroll
            for (int rt = 0; rt < 4; ++rt) {
                acc[rt] = __builtin_amdgcn_mfma_f32_16x16x32_bf16(wa_hi[rt][0].v, hb[0].v, u[rt],  0, 0, 0);
                acc[rt] = __builtin_amdgcn_mfma_f32_16x16x32_bf16(wa_lo[rt][0].v, hb[0].v, acc[rt], 0, 0, 0);
                acc[rt] = __builtin_amdgcn_mfma_f32_16x16x32_bf16(wa_hi[rt][1].v, hb[1].v, acc[rt], 0, 0, 0);
                acc[rt] = __builtin_amdgcn_mfma_f32_16x16x32_bf16(wa_lo[rt][1].v, hb[1].v, acc[rt], 0, 0, 0);
            }

            // elementwise: tanh + leaky mix; pack to bf16 pairs
            int pk[4][2];
#pragma unroll
            for (int rt = 0; rt < 4; ++rt) {
                f32x4 hn;
#pragma unroll
                for (int r = 0; r < 4; ++r) {
                    const float z  = acc[rt][r];
                    const float e  = __builtin_amdgcn_exp2f(z * 2.8853900817779268f); // exp(2z)
                    const float rc = __builtin_amdgcn_rcpf(1.0f + e);                 // tanh = 1-2rc
                    hn[r] = fmaf(-omd2_v[rt][r], rc,
                                 fmaf(hd[rt][r], decay_v[rt][r], omd_v[rt][r]));
                }
                hd[rt] = hn;
                asm("v_cvt_pk_bf16_f32 %0, %1, %2" : "=v"(pk[rt][0]) : "v"(hn[0]), "v"(hn[1]));
                asm("v_cvt_pk_bf16_f32 %0, %1, %2" : "=v"(pk[rt][1]) : "v"(hn[2]), "v"(hn[3]));
            }

            // in-register D->B transpose: 16 bpermute + 8 cndmask
#pragma unroll
            for (int ks = 0; ks < 2; ++ks) {
                int lo, hi;
                lo = __builtin_amdgcn_ds_bpermute(aE, pk[2 * ks][0]);
                hi = __builtin_amdgcn_ds_bpermute(aE, pk[2 * ks + 1][0]);
                hb[ks].i[0] = lohalf ? lo : hi;
                lo = __builtin_amdgcn_ds_bpermute(aE, pk[2 * ks][1]);
                hi = __builtin_amdgcn_ds_bpermute(aE, pk[2 * ks + 1][1]);
                hb[ks].i[1] = lohalf ? lo : hi;
                lo = __builtin_amdgcn_ds_bpermute(aO, pk[2 * ks][0]);
                hi = __builtin_amdgcn_ds_bpermute(aO, pk[2 * ks + 1][0]);
                hb[ks].i[2] = lohalf ? lo : hi;
                lo = __builtin_amdgcn_ds_bpermute(aO, pk[2 * ks][1]);
                hi = __builtin_amdgcn_ds_bpermute(aO, pk[2 * ks + 1][1]);
                hb[ks].i[3] = lohalf ? lo : hi;
            }
        }

        // classifier: p[c] = sum_n h[n][c]*W_cls[n] + bc
        float p = 0.f;
#pragma unroll
        for (int rt = 0; rt < 4; ++rt)
#pragma unroll
            for (int r = 0; r < 4; ++r)
                p = fmaf(hd[rt][r], wc_v[rt][r], p);
        p += __shfl_xor(p, 16);
        p += __shfl_xor(p, 32);
        if (g == 0) out[(size_t)(b0 + c) * T_LEN + t] = p + bc;

        x0 = n0; x1 = n1; x2 = n2; x3 = n3; x4 = n4; x5 = n5;
    }
}

extern "C" void kernel_launch(void* const* d_in, const int* in_sizes, int n_in,
                              void* d_out, int out_size, void* d_ws, size_t ws_size,
                              hipStream_t stream) {
    const float* x_seq = (const float*)d_in[0];
    const float* dt_p  = (const float*)d_in[1];
    const float* W_in  = (const float*)d_in[2];
    const float* b_in  = (const float*)d_in[3];
    const float* W_rec = (const float*)d_in[4];
    const float* b_rec = (const float*)d_in[5];
    const float* tau   = (const float*)d_in[6];
    const float* W_cls = (const float*)d_in[7];
    const float* b_cls = (const float*)d_in[8];
    const int*   ode_s = (const int*)d_in[9];
    float* outp = (float*)d_out;

    const int B = in_sizes[0] / (T_LEN * F_DIM);  // 4096
    const int grid = (B + BPW - 1) / BPW;         // 256 blocks x 1 wave

    liquid_rnn_mfma<<<grid, 64, 0, stream>>>(x_seq, dt_p, W_in, b_in, W_rec, b_rec,
                                             tau, W_cls, b_cls, ode_s, outp, B);
}

// Round 5
// 653.800 us; speedup vs baseline: 2.4825x; 2.3645x over previous
//
#include <hip/hip_runtime.h>

#define T_LEN 512
#define F_DIM 6
#define H_DIM 64
#define BPW   16   // batches per block (= mfma N dimension)

typedef short  bf16x8 __attribute__((ext_vector_type(8)));
typedef float  f32x4  __attribute__((ext_vector_type(4)));

static __device__ __forceinline__ unsigned short f2bf(float f) {
    unsigned u = __builtin_bit_cast(unsigned, f);
    u += 0x7FFFu + ((u >> 16) & 1u);   // RNE
    return (unsigned short)(u >> 16);
}
static __device__ __forceinline__ float bf2f(unsigned short h) {
    return __builtin_bit_cast(float, ((unsigned)h) << 16);
}
static __device__ __forceinline__ float bflo(int w) {
    return __builtin_bit_cast(float, (unsigned)w << 16);
}
static __device__ __forceinline__ float bfhi(int w) {
    return __builtin_bit_cast(float, (unsigned)w & 0xFFFF0000u);
}

union frag_u { bf16x8 v; int i[4]; unsigned short s[8]; };

static __device__ __forceinline__ void build_xfrag(frag_u& xh, frag_u& xl,
    float v0, float v1, float v2, float v3, float v4, float v5) {
#define SX(i, val) { unsigned short hh = f2bf(val); xh.s[i] = (short)hh; xl.s[i] = (short)f2bf((val) - bf2f(hh)); }
    SX(0, v0) SX(1, v1) SX(2, v2) SX(3, v3) SX(4, v4) SX(5, v5)
#undef SX
    xh.s[6] = xh.s[7] = xl.s[6] = xl.s[7] = 0;
}

// 4 waves per block; wave w owns output rows [16w, 16w+16) of the 64x16 state.
// h exchanged between waves per ode step via 2x512-dword LDS (XOR-swizzled).
__global__ __launch_bounds__(256, 1) void liquid_rnn_mfma4(
    const float* __restrict__ x_seq, const float* __restrict__ dt_p,
    const float* __restrict__ W_in,  const float* __restrict__ b_in,
    const float* __restrict__ W_rec, const float* __restrict__ b_rec,
    const float* __restrict__ tau,   const float* __restrict__ W_cls,
    const float* __restrict__ b_cls, const int* __restrict__ ode_steps_p,
    float* __restrict__ out, int B)
{
    const int tid = threadIdx.x;
    const int w = tid >> 6;      // wave 0..3  -> row tile
    const int l = tid & 63;
    const int c = l & 15;        // batch column
    const int g = l >> 4;        // lane group
    const int b0 = blockIdx.x * BPW;
    if (b0 >= B) return;

    __shared__ __align__(16) int lds[1024];   // 2 buffers x 512 dwords

    const int   ode_steps = ode_steps_p[0];
    const float steps_dt  = dt_p[0] / (float)ode_steps;
    const float bc        = b_cls[0];
    const f32x4 zero4 = {0.f, 0.f, 0.f, 0.f};

    // per-lane row constants: n = 16w + 4g + r
    float decay_v[4], omd_v[4], omd2_v[4];
    f32x4 bias_c;
#pragma unroll
    for (int r = 0; r < 4; ++r) {
        const int n = 16 * w + 4 * g + r;
        const float d = __expf(-steps_dt / fabsf(tau[n]));
        decay_v[r] = d; omd_v[r] = 1.f - d; omd2_v[r] = 2.f * (1.f - d);
        bias_c[r] = b_in[n] + b_rec[n];
    }

    // W_rec A-frags (hi/lo bf16 split) for rows 16w..16w+15
    frag_u wa_hi[2], wa_lo[2];
#pragma unroll
    for (int ks = 0; ks < 2; ++ks)
#pragma unroll
        for (int i = 0; i < 8; ++i) {
            const float wv = W_rec[(16 * w + c) * H_DIM + 32 * ks + 8 * g + i];
            const unsigned short hh = f2bf(wv);
            wa_hi[ks].s[i] = (short)hh;
            wa_lo[ks].s[i] = (short)f2bf(wv - bf2f(hh));
        }

    // W_in A-frags (K padded 6->32: valid iff g==0 && i<6)
    frag_u wu_hi, wu_lo;
#pragma unroll
    for (int i = 0; i < 8; ++i) {
        const float wv = (g == 0 && i < F_DIM) ? W_in[(16 * w + c) * F_DIM + i] : 0.f;
        const unsigned short hh = f2bf(wv);
        wu_hi.s[i] = (short)hh;
        wu_lo.s[i] = (short)f2bf(wv - bf2f(hh));
    }

    // classifier weights as bf16 pairs matching hb dword order (wave 0 uses)
    int wcb[8];
#pragma unroll
    for (int ks = 0; ks < 2; ++ks)
#pragma unroll
        for (int j2 = 0; j2 < 4; ++j2) {
            const int n0 = 2 * (16 * ks + 4 * g + j2);
            wcb[ks * 4 + j2] = (int)f2bf(W_cls[n0]) | ((int)f2bf(W_cls[n0 + 1]) << 16);
        }

    // LDS dword addresses: D(c,kp) = c*32 + (kp ^ ((c&7)<<2))
    // write pairs kp = 8w+2g+{0,1}; read hb[ks] = kp 16ks+4g+{0..3}
    const int xsw   = (c & 7) << 2;
    const int wr_dw = c * 32 + ((8 * w + 2 * g) ^ xsw);
    const int rd0   = c * 32 + ((4 * g) ^ xsw);
    const int rd1   = c * 32 + ((16 + 4 * g) ^ xsw);

    // state
    f32x4 hd = zero4;              // f32 h for own rows (decay path)
    frag_u hb[2];                  // full h, bf16 B-frags
    hb[0].i[0]=hb[0].i[1]=hb[0].i[2]=hb[0].i[3]=0;
    hb[1].i[0]=hb[1].i[1]=hb[1].i[2]=hb[1].i[3]=0;

    const float* xr = x_seq + (size_t)(b0 + c) * T_LEN * F_DIM;

    // prologue: x(0) -> u_cur
    float xa0=0,xa1=0,xa2=0,xa3=0,xa4=0,xa5=0;
    if (g == 0) { xa0=xr[0]; xa1=xr[1]; xa2=xr[2]; xa3=xr[3]; xa4=xr[4]; xa5=xr[5]; }
    f32x4 u_cur;
    {
        frag_u xh, xl; build_xfrag(xh, xl, xa0,xa1,xa2,xa3,xa4,xa5);
        f32x4 m1 = __builtin_amdgcn_mfma_f32_16x16x32_bf16(wu_hi.v, xh.v, bias_c, 0,0,0);
        f32x4 m2 = __builtin_amdgcn_mfma_f32_16x16x32_bf16(wu_hi.v, xl.v, zero4, 0,0,0);
        f32x4 m3 = __builtin_amdgcn_mfma_f32_16x16x32_bf16(wu_lo.v, xh.v, zero4, 0,0,0);
        u_cur = (m1 + m2) + m3;
    }

    for (int t = 0; t < T_LEN; ++t) {
        // prefetch x(t+1); consumed after the ode loop (latency hidden)
        float nn0=0,nn1=0,nn2=0,nn3=0,nn4=0,nn5=0;
        if (g == 0) {
            const float* xn = xr + (size_t)((t + 1 < T_LEN) ? t + 1 : t) * F_DIM;
            nn0=xn[0]; nn1=xn[1]; nn2=xn[2]; nn3=xn[3]; nn4=xn[4]; nn5=xn[5];
        }

        for (int s = 0; s < ode_steps; ++s) {
            // z = u + (W_hi+W_lo)·h : 4 INDEPENDENT mfmas, tree add (short chain)
            f32x4 a0 = __builtin_amdgcn_mfma_f32_16x16x32_bf16(wa_hi[0].v, hb[0].v, u_cur, 0,0,0);
            f32x4 a1 = __builtin_amdgcn_mfma_f32_16x16x32_bf16(wa_hi[1].v, hb[1].v, zero4, 0,0,0);
            f32x4 a2 = __builtin_amdgcn_mfma_f32_16x16x32_bf16(wa_lo[0].v, hb[0].v, zero4, 0,0,0);
            f32x4 a3 = __builtin_amdgcn_mfma_f32_16x16x32_bf16(wa_lo[1].v, hb[1].v, zero4, 0,0,0);
            f32x4 z = (a0 + a1) + (a2 + a3);

            // elementwise (4 values/lane): tanh = 1 - 2*rcp(1+exp(2z))
            f32x4 hn;
#pragma unroll
            for (int r = 0; r < 4; ++r) {
                const float e  = __builtin_amdgcn_exp2f(z[r] * 2.8853900817779268f);
                const float rc = __builtin_amdgcn_rcpf(1.0f + e);
                hn[r] = fmaf(-omd2_v[r], rc, fmaf(hd[r], decay_v[r], omd_v[r]));
            }
            hd = hn;

            int pk0, pk1;
            asm("v_cvt_pk_bf16_f32 %0, %1, %2" : "=v"(pk0) : "v"(hn[0]), "v"(hn[1]));
            asm("v_cvt_pk_bf16_f32 %0, %1, %2" : "=v"(pk1) : "v"(hn[2]), "v"(hn[3]));

            // cross-wave exchange (double-buffered; raw barrier: NO vmcnt drain)
            const int buf = (s & 1) << 9;
            *(int2*)&lds[buf + wr_dw] = make_int2(pk0, pk1);
            asm volatile("s_waitcnt lgkmcnt(0)" ::: "memory");   // writes visible
            __builtin_amdgcn_s_barrier();
            asm volatile("" ::: "memory");                        // no read hoisting
            const int4 q0 = *(const int4*)&lds[buf + rd0];
            const int4 q1 = *(const int4*)&lds[buf + rd1];
            hb[0].i[0]=q0.x; hb[0].i[1]=q0.y; hb[0].i[2]=q0.z; hb[0].i[3]=q0.w;
            hb[1].i[0]=q1.x; hb[1].i[1]=q1.y; hb[1].i[2]=q1.z; hb[1].i[3]=q1.w;
        }

        // u(t+1): off the recurrent chain
        {
            frag_u xh, xl; build_xfrag(xh, xl, nn0,nn1,nn2,nn3,nn4,nn5);
            f32x4 m1 = __builtin_amdgcn_mfma_f32_16x16x32_bf16(wu_hi.v, xh.v, bias_c, 0,0,0);
            f32x4 m2 = __builtin_amdgcn_mfma_f32_16x16x32_bf16(wu_hi.v, xl.v, zero4, 0,0,0);
            f32x4 m3 = __builtin_amdgcn_mfma_f32_16x16x32_bf16(wu_lo.v, xh.v, zero4, 0,0,0);
            u_cur = (m1 + m2) + m3;
        }

        // classifier (wave 0 only): p[c] = sum_n h_bf16[n][c]*W_cls[n]
        if (w == 0) {
            float p = 0.f;
#pragma unroll
            for (int ks = 0; ks < 2; ++ks)
#pragma unroll
                for (int j2 = 0; j2 < 4; ++j2) {
                    const int hw = hb[ks].i[j2], wv = wcb[ks * 4 + j2];
                    p = fmaf(bflo(hw), bflo(wv), p);
                    p = fmaf(bfhi(hw), bfhi(wv), p);
                }
            p += __shfl_xor(p, 16);
            p += __shfl_xor(p, 32);
            if (g == 0) out[(size_t)(b0 + c) * T_LEN + t] = p + bc;
        }
    }
}

extern "C" void kernel_launch(void* const* d_in, const int* in_sizes, int n_in,
                              void* d_out, int out_size, void* d_ws, size_t ws_size,
                              hipStream_t stream) {
    const float* x_seq = (const float*)d_in[0];
    const float* dt_p  = (const float*)d_in[1];
    const float* W_in  = (const float*)d_in[2];
    const float* b_in  = (const float*)d_in[3];
    const float* W_rec = (const float*)d_in[4];
    const float* b_rec = (const float*)d_in[5];
    const float* tau   = (const float*)d_in[6];
    const float* W_cls = (const float*)d_in[7];
    const float* b_cls = (const float*)d_in[8];
    const int*   ode_s = (const int*)d_in[9];
    float* outp = (float*)d_out;

    const int B = in_sizes[0] / (T_LEN * F_DIM);  // 4096
    const int grid = (B + BPW - 1) / BPW;         // 256 blocks x 4 waves

    liquid_rnn_mfma4<<<grid, 256, 0, stream>>>(x_seq, dt_p, W_in, b_in, W_rec, b_rec,
                                               tau, W_cls, b_cls, ode_s, outp, B);
}

// Round 6
// 570.827 us; speedup vs baseline: 2.8433x; 1.1454x over previous
//
#include <hip/hip_runtime.h>

#define T_LEN 512
#define F_DIM 6
#define H_DIM 64
#define BPW   16   // batches per block (= mfma N dimension)

typedef _Float16 f16x8 __attribute__((ext_vector_type(8)));
typedef _Float16 f16x2 __attribute__((ext_vector_type(2)));
typedef float    f32x4 __attribute__((ext_vector_type(4)));

union frag_u { f16x8 v; int i[4]; _Float16 h[8]; };

// One ODE sub-step: 2 f16 mfma -> tanh/mix (4 vals/lane) -> f16 pack ->
// swizzled LDS exchange (raw barrier, no vmcnt drain) -> reload B-frags.
#define ODE_BODY(BUF) do {                                                      \
    f32x4 a0 = __builtin_amdgcn_mfma_f32_16x16x32_f16(wa[0].v, hb[0].v, u_cur, 0,0,0); \
    f32x4 a1 = __builtin_amdgcn_mfma_f32_16x16x32_f16(wa[1].v, hb[1].v, zero4, 0,0,0); \
    f32x4 z = a0 + a1;                                                          \
    f32x4 hn;                                                                   \
    _Pragma("unroll")                                                           \
    for (int r = 0; r < 4; ++r) {                                               \
        const float e  = __builtin_amdgcn_exp2f(z[r] * 2.8853900817779268f);    \
        const float rc = __builtin_amdgcn_rcpf(1.0f + e);                       \
        hn[r] = fmaf(-omd2_v[r], rc, fmaf(hd[r], decay_v[r], omd_v[r]));        \
    }                                                                           \
    hd = hn;                                                                    \
    f16x2 pa, pb;                                                               \
    pa.x = (_Float16)hn[0]; pa.y = (_Float16)hn[1];                             \
    pb.x = (_Float16)hn[2]; pb.y = (_Float16)hn[3];                             \
    *(int2*)&lds[(BUF) + wr_dw] =                                               \
        make_int2(__builtin_bit_cast(int, pa), __builtin_bit_cast(int, pb));    \
    asm volatile("s_waitcnt lgkmcnt(0)" ::: "memory");                          \
    __builtin_amdgcn_s_barrier();                                               \
    asm volatile("" ::: "memory");                                              \
    const int4 q0 = *(const int4*)&lds[(BUF) + rd0];                            \
    const int4 q1 = *(const int4*)&lds[(BUF) + rd1];                            \
    hb[0].i[0]=q0.x; hb[0].i[1]=q0.y; hb[0].i[2]=q0.z; hb[0].i[3]=q0.w;         \
    hb[1].i[0]=q1.x; hb[1].i[1]=q1.y; hb[1].i[2]=q1.z; hb[1].i[3]=q1.w;         \
} while (0)

// Off-chain work hidden in the step-0 barrier/LDS-read shadow:
// u(t+1) mfma from xA, advance x pipeline, issue x(t+3) loads.
#define SHADOW_U_AND_PREFETCH do {                                              \
    frag_u xf;                                                                  \
    xf.i[0] = __builtin_bit_cast(int, __builtin_amdgcn_cvt_pkrtz(xA[0], xA[1]));\
    xf.i[1] = __builtin_bit_cast(int, __builtin_amdgcn_cvt_pkrtz(xA[2], xA[3]));\
    xf.i[2] = __builtin_bit_cast(int, __builtin_amdgcn_cvt_pkrtz(xA[4], xA[5]));\
    xf.i[3] = 0;                                                                \
    u_next = __builtin_amdgcn_mfma_f32_16x16x32_f16(wu.v, xf.v, bias_c, 0,0,0); \
    _Pragma("unroll")                                                           \
    for (int f2 = 0; f2 < F_DIM; ++f2) xA[f2] = xB[f2];                         \
    if (g == 0) {                                                               \
        int tn = t + 3; if (tn > T_LEN - 1) tn = T_LEN - 1;                     \
        const float* pfx = xr + (size_t)tn * F_DIM;                             \
        _Pragma("unroll")                                                       \
        for (int f2 = 0; f2 < F_DIM; ++f2) xB[f2] = pfx[f2];                    \
    }                                                                           \
} while (0)

__global__ __launch_bounds__(256, 1) void liquid_rnn_f16(
    const float* __restrict__ x_seq, const float* __restrict__ dt_p,
    const float* __restrict__ W_in,  const float* __restrict__ b_in,
    const float* __restrict__ W_rec, const float* __restrict__ b_rec,
    const float* __restrict__ tau,   const float* __restrict__ W_cls,
    const float* __restrict__ b_cls, const int* __restrict__ ode_steps_p,
    float* __restrict__ out, int B)
{
    const int tid = threadIdx.x;
    const int w = tid >> 6;      // wave 0..3 -> row tile [16w,16w+16)
    const int l = tid & 63;
    const int c = l & 15;        // batch column
    const int g = l >> 4;        // lane group
    const int b0 = blockIdx.x * BPW;
    if (b0 >= B) return;

    __shared__ __align__(16) int lds[1024];   // 2 buffers x 512 dwords

    const int   ode_steps = ode_steps_p[0];
    const float steps_dt  = dt_p[0] / (float)ode_steps;
    const float bc        = b_cls[0];
    const f32x4 zero4 = {0.f, 0.f, 0.f, 0.f};

    // per-lane row constants: n = 16w + 4g + r
    float decay_v[4], omd_v[4], omd2_v[4];
    f32x4 bias_c;
#pragma unroll
    for (int r = 0; r < 4; ++r) {
        const int n = 16 * w + 4 * g + r;
        const float d = __expf(-steps_dt / fabsf(tau[n]));
        decay_v[r] = d; omd_v[r] = 1.f - d; omd2_v[r] = 2.f * (1.f - d);
        bias_c[r] = b_in[n] + b_rec[n];
    }

    // W_rec A-frags, single f16 precision (round-2 numerics)
    frag_u wa[2];
#pragma unroll
    for (int ks = 0; ks < 2; ++ks)
#pragma unroll
        for (int i = 0; i < 8; ++i)
            wa[ks].h[i] = (_Float16)W_rec[(16 * w + c) * H_DIM + 32 * ks + 8 * g + i];

    // W_in A-frag (K padded 6->32: zero unless g==0 && i<6; zeros kill garbage B)
    frag_u wu;
#pragma unroll
    for (int i = 0; i < 8; ++i)
        wu.h[i] = (g == 0 && i < F_DIM) ? (_Float16)W_in[(16 * w + c) * F_DIM + i]
                                        : (_Float16)0.f;

    // classifier weights as f16 pairs matching hb dword order
    int wcf[8];
#pragma unroll
    for (int ks = 0; ks < 2; ++ks)
#pragma unroll
        for (int j = 0; j < 4; ++j) {
            const int n0 = 2 * (16 * ks + 4 * g + j);
            f16x2 pr; pr.x = (_Float16)W_cls[n0]; pr.y = (_Float16)W_cls[n0 + 1];
            wcf[ks * 4 + j] = __builtin_bit_cast(int, pr);
        }

    // LDS dword addresses: D(c,kp) = c*32 + (kp ^ ((c&7)<<2))
    // write pairs kp = 8w+2g+{0,1}; read hb[ks] = kp 16ks+4g+{0..3}
    const int xsw   = (c & 7) << 2;
    const int wr_dw = c * 32 + ((8 * w + 2 * g) ^ xsw);
    const int rd0   = c * 32 + ((4 * g) ^ xsw);
    const int rd1   = c * 32 + ((16 + 4 * g) ^ xsw);

    // state
    f32x4 hd = zero4;              // f32 h for own rows (decay path)
    frag_u hb[2];                  // full h, f16 B-frags
    hb[0].i[0]=hb[0].i[1]=hb[0].i[2]=hb[0].i[3]=0;
    hb[1].i[0]=hb[1].i[1]=hb[1].i[2]=hb[1].i[3]=0;

    const float* xr = x_seq + (size_t)(b0 + c) * T_LEN * F_DIM;

    // prologue: u(0) directly; x pipeline xA=x(1), xB=x(2)
    f32x4 u_cur;
    {
        float x0=0,x1=0,x2=0,x3=0,x4=0,x5=0;
        if (g == 0) { x0=xr[0]; x1=xr[1]; x2=xr[2]; x3=xr[3]; x4=xr[4]; x5=xr[5]; }
        frag_u xf;
        xf.i[0] = __builtin_bit_cast(int, __builtin_amdgcn_cvt_pkrtz(x0, x1));
        xf.i[1] = __builtin_bit_cast(int, __builtin_amdgcn_cvt_pkrtz(x2, x3));
        xf.i[2] = __builtin_bit_cast(int, __builtin_amdgcn_cvt_pkrtz(x4, x5));
        xf.i[3] = 0;
        u_cur = __builtin_amdgcn_mfma_f32_16x16x32_f16(wu.v, xf.v, bias_c, 0,0,0);
    }
    float xA[F_DIM] = {0,0,0,0,0,0}, xB[F_DIM] = {0,0,0,0,0,0};
    if (g == 0) {
        const float* p1 = xr + 1 * F_DIM;
        const float* p2 = xr + 2 * F_DIM;
#pragma unroll
        for (int f = 0; f < F_DIM; ++f) { xA[f] = p1[f]; xB[f] = p2[f]; }
    }

    for (int t = 0; t < T_LEN; ++t) {
        f32x4 u_next;
        if (ode_steps == 4) {
            ODE_BODY(0);
            SHADOW_U_AND_PREFETCH;     // hidden under step-0/1 LDS+barrier latency
            ODE_BODY(512);
            ODE_BODY(0);
            ODE_BODY(512);
        } else {
            for (int s = 0; s < ode_steps; ++s) {
                const int buf = (s & 1) << 9;
                ODE_BODY(buf);
            }
            if (ode_steps & 1) __syncthreads();   // keep buffer parity safe
            SHADOW_U_AND_PREFETCH;
        }
        u_cur = u_next;

        // classifier: ALL waves compute (identical work, no barrier skew);
        // p[c] = sum_n h_f16[n][c] * W_cls[n]  via 8 fdot2
        float p = 0.f;
#pragma unroll
        for (int ks = 0; ks < 2; ++ks)
#pragma unroll
            for (int j = 0; j < 4; ++j)
                p = __builtin_amdgcn_fdot2(
                        __builtin_bit_cast(f16x2, hb[ks].i[j]),
                        __builtin_bit_cast(f16x2, wcf[ks * 4 + j]), p, false);
        p += __shfl_xor(p, 16);
        p += __shfl_xor(p, 32);
        if (w == 0 && g == 0) out[(size_t)(b0 + c) * T_LEN + t] = p + bc;
    }
}

extern "C" void kernel_launch(void* const* d_in, const int* in_sizes, int n_in,
                              void* d_out, int out_size, void* d_ws, size_t ws_size,
                              hipStream_t stream) {
    const float* x_seq = (const float*)d_in[0];
    const float* dt_p  = (const float*)d_in[1];
    const float* W_in  = (const float*)d_in[2];
    const float* b_in  = (const float*)d_in[3];
    const float* W_rec = (const float*)d_in[4];
    const float* b_rec = (const float*)d_in[5];
    const float* tau   = (const float*)d_in[6];
    const float* W_cls = (const float*)d_in[7];
    const float* b_cls = (const float*)d_in[8];
    const int*   ode_s = (const int*)d_in[9];
    float* outp = (float*)d_out;

    const int B = in_sizes[0] / (T_LEN * F_DIM);  // 4096
    const int grid = (B + BPW - 1) / BPW;         // 256 blocks x 4 waves

    liquid_rnn_f16<<<grid, 256, 0, stream>>>(x_seq, dt_p, W_in, b_in, W_rec, b_rec,
                                             tau, W_cls, b_cls, ode_s, outp, B);
}

// Round 7
// 506.482 us; speedup vs baseline: 3.2045x; 1.1270x over previous
//
#include <hip/hip_runtime.h>

#define T_LEN 512
#define F_DIM 6
#define H_DIM 64
#define BPW   16   // batches per block (= mfma N dimension)

typedef _Float16 f16x8 __attribute__((ext_vector_type(8)));
typedef _Float16 f16x2 __attribute__((ext_vector_type(2)));
typedef float    f32x4 __attribute__((ext_vector_type(4)));

#define SC 2.8853900817779268f   // 2*log2(e), folded into W/bias scaling

union frag_u { f16x8 v; int4 q; int i[4]; _Float16 h[8]; };

// One ODE sub-step. Weights pre-scaled by SC, so mfma emits z' = 2*log2e*z
// and tanh(z) = 1 - 2*rcp(1+exp2(z')).
#define ODE_BODY(BUF) do {                                                      \
    f32x4 a0 = __builtin_amdgcn_mfma_f32_16x16x32_f16(wa[0].v, hb[0].v, u_cur, 0,0,0); \
    f32x4 a1 = __builtin_amdgcn_mfma_f32_16x16x32_f16(wa[1].v, hb[1].v, zero4, 0,0,0); \
    f32x4 zz = a0 + a1;                                                         \
    f32x4 hn;                                                                   \
    _Pragma("unroll")                                                           \
    for (int r = 0; r < 4; ++r) {                                               \
        const float e  = __builtin_amdgcn_exp2f(zz[r]);                         \
        const float rc = __builtin_amdgcn_rcpf(1.0f + e);                       \
        hn[r] = fmaf(-omd2_v[r], rc, fmaf(hd[r], decay_v[r], omd_v[r]));        \
    }                                                                           \
    hd = hn;                                                                    \
    f16x2 pa, pb;                                                               \
    pa.x = (_Float16)hn[0]; pa.y = (_Float16)hn[1];                             \
    pb.x = (_Float16)hn[2]; pb.y = (_Float16)hn[3];                             \
    *(int2*)&lds[(BUF) + wr_dw] =                                               \
        make_int2(__builtin_bit_cast(int, pa), __builtin_bit_cast(int, pb));    \
    asm volatile("s_waitcnt lgkmcnt(0)" ::: "memory");                          \
    __builtin_amdgcn_s_barrier();                                               \
    asm volatile("" ::: "memory");                                              \
    hb[0].q = *(const int4*)&lds[(BUF) + rd0];                                  \
    hb[1].q = *(const int4*)&lds[(BUF) + rd1];                                  \
} while (0)

// Off-chain work in the step-0 ds_read latency shadow:
// (1) finish+store t-1's classifier, (2) u(t+1) mfma, (3) x pipeline advance.
#define SHADOW_BLOCK do {                                                       \
    float pr = p_pend;                                                          \
    pr += __shfl_xor(pr, 16);                                                   \
    pr += __shfl_xor(pr, 32);                                                   \
    if (t > 0 && w == 0 && g == 0)                                              \
        out[(size_t)(b0 + c) * T_LEN + (t - 1)] = pr + bc;                      \
    frag_u xf;                                                                  \
    xf.i[0] = __builtin_bit_cast(int, __builtin_amdgcn_cvt_pkrtz(xA[0], xA[1]));\
    xf.i[1] = __builtin_bit_cast(int, __builtin_amdgcn_cvt_pkrtz(xA[2], xA[3]));\
    xf.i[2] = __builtin_bit_cast(int, __builtin_amdgcn_cvt_pkrtz(xA[4], xA[5]));\
    xf.i[3] = 0;                                                                \
    u_next = __builtin_amdgcn_mfma_f32_16x16x32_f16(wu.v, xf.v, bias_c, 0,0,0); \
    _Pragma("unroll")                                                           \
    for (int f2 = 0; f2 < F_DIM; ++f2) xA[f2] = xB[f2];                         \
    if (g == 0) {                                                               \
        int tn = t + 3; if (tn > T_LEN - 1) tn = T_LEN - 1;                     \
        const float* pfx = xr + (size_t)tn * F_DIM;                             \
        _Pragma("unroll")                                                       \
        for (int f2 = 0; f2 < F_DIM; ++f2) xB[f2] = pfx[f2];                    \
    }                                                                           \
} while (0)

__global__ __launch_bounds__(256, 1) void liquid_rnn_f16(
    const float* __restrict__ x_seq, const float* __restrict__ dt_p,
    const float* __restrict__ W_in,  const float* __restrict__ b_in,
    const float* __restrict__ W_rec, const float* __restrict__ b_rec,
    const float* __restrict__ tau,   const float* __restrict__ W_cls,
    const float* __restrict__ b_cls, const int* __restrict__ ode_steps_p,
    float* __restrict__ out, int B)
{
    const int tid = threadIdx.x;
    const int w = tid >> 6;      // wave 0..3 -> row tile [16w,16w+16)
    const int l = tid & 63;
    const int c = l & 15;        // batch column
    const int g = l >> 4;        // lane group
    const int b0 = blockIdx.x * BPW;
    if (b0 >= B) return;

    __shared__ __align__(16) int lds[1024];   // 2 buffers x 512 dwords

    const int   ode_steps = ode_steps_p[0];
    const float steps_dt  = dt_p[0] / (float)ode_steps;
    const float bc        = b_cls[0];
    const f32x4 zero4 = {0.f, 0.f, 0.f, 0.f};

    // per-lane row constants: n = 16w + 4g + r
    float decay_v[4], omd_v[4], omd2_v[4];
    f32x4 bias_c;
#pragma unroll
    for (int r = 0; r < 4; ++r) {
        const int n = 16 * w + 4 * g + r;
        const float d = __expf(-steps_dt / fabsf(tau[n]));
        decay_v[r] = d; omd_v[r] = 1.f - d; omd2_v[r] = 2.f * (1.f - d);
        bias_c[r] = SC * (b_in[n] + b_rec[n]);
    }

    // W_rec A-frags, f16, pre-scaled by SC
    frag_u wa[2];
#pragma unroll
    for (int ks = 0; ks < 2; ++ks)
#pragma unroll
        for (int i = 0; i < 8; ++i)
            wa[ks].h[i] = (_Float16)(SC * W_rec[(16 * w + c) * H_DIM + 32 * ks + 8 * g + i]);

    // W_in A-frag (K padded 6->32), pre-scaled by SC
    frag_u wu;
#pragma unroll
    for (int i = 0; i < 8; ++i)
        wu.h[i] = (g == 0 && i < F_DIM) ? (_Float16)(SC * W_in[(16 * w + c) * F_DIM + i])
                                        : (_Float16)0.f;

    // classifier weights as f16 pairs matching hb dword order (unscaled)
    int wcf[8];
#pragma unroll
    for (int ks = 0; ks < 2; ++ks)
#pragma unroll
        for (int j = 0; j < 4; ++j) {
            const int n0 = 2 * (16 * ks + 4 * g + j);
            f16x2 pr; pr.x = (_Float16)W_cls[n0]; pr.y = (_Float16)W_cls[n0 + 1];
            wcf[ks * 4 + j] = __builtin_bit_cast(int, pr);
        }

    // LDS dword addresses: D(c,kp) = c*32 + (kp ^ ((c&7)<<2))
    const int xsw   = (c & 7) << 2;
    const int wr_dw = c * 32 + ((8 * w + 2 * g) ^ xsw);
    const int rd0   = c * 32 + ((4 * g) ^ xsw);
    const int rd1   = c * 32 + ((16 + 4 * g) ^ xsw);

    // state
    f32x4 hd = zero4;              // f32 h for own rows
    frag_u hb[2];                  // full h, f16 B-frags
    hb[0].i[0]=hb[0].i[1]=hb[0].i[2]=hb[0].i[3]=0;
    hb[1].i[0]=hb[1].i[1]=hb[1].i[2]=hb[1].i[3]=0;

    const float* xr = x_seq + (size_t)(b0 + c) * T_LEN * F_DIM;

    // prologue: u(0); x pipeline xA=x(1), xB=x(2)
    f32x4 u_cur;
    {
        float x0=0,x1=0,x2=0,x3=0,x4=0,x5=0;
        if (g == 0) { x0=xr[0]; x1=xr[1]; x2=xr[2]; x3=xr[3]; x4=xr[4]; x5=xr[5]; }
        frag_u xf;
        xf.i[0] = __builtin_bit_cast(int, __builtin_amdgcn_cvt_pkrtz(x0, x1));
        xf.i[1] = __builtin_bit_cast(int, __builtin_amdgcn_cvt_pkrtz(x2, x3));
        xf.i[2] = __builtin_bit_cast(int, __builtin_amdgcn_cvt_pkrtz(x4, x5));
        xf.i[3] = 0;
        u_cur = __builtin_amdgcn_mfma_f32_16x16x32_f16(wu.v, xf.v, bias_c, 0,0,0);
    }
    float xA[F_DIM] = {0,0,0,0,0,0}, xB[F_DIM] = {0,0,0,0,0,0};
    if (g == 0) {
        const float* p1 = xr + 1 * F_DIM;
        const float* p2 = xr + 2 * F_DIM;
#pragma unroll
        for (int f = 0; f < F_DIM; ++f) { xA[f] = p1[f]; xB[f] = p2[f]; }
    }

    float p_pend = 0.f;

    for (int t = 0; t < T_LEN; ++t) {
        f32x4 u_next;
        if (ode_steps == 4) {
            ODE_BODY(0);
            SHADOW_BLOCK;              // t-1 classifier finish + u(t+1) + prefetch,
            ODE_BODY(512);             // all hidden under step-0/1 exchange latency
            ODE_BODY(0);
            ODE_BODY(512);
        } else {
            for (int s = 0; s < ode_steps; ++s) {
                const int buf = (s & 1) << 9;
                ODE_BODY(buf);
            }
            if (ode_steps & 1) __syncthreads();
            SHADOW_BLOCK;
        }
        u_cur = u_next;

        // t-end: only the cheap partial (8 fdot2); reduction deferred to shadow
        float p = 0.f;
#pragma unroll
        for (int ks = 0; ks < 2; ++ks)
#pragma unroll
            for (int j = 0; j < 4; ++j)
                p = __builtin_amdgcn_fdot2(
                        __builtin_bit_cast(f16x2, hb[ks].i[j]),
                        __builtin_bit_cast(f16x2, wcf[ks * 4 + j]), p, false);
        p_pend = p;
    }

    // final t = T_LEN-1 classifier
    p_pend += __shfl_xor(p_pend, 16);
    p_pend += __shfl_xor(p_pend, 32);
    if (w == 0 && g == 0) out[(size_t)(b0 + c) * T_LEN + (T_LEN - 1)] = p_pend + bc;
}

extern "C" void kernel_launch(void* const* d_in, const int* in_sizes, int n_in,
                              void* d_out, int out_size, void* d_ws, size_t ws_size,
                              hipStream_t stream) {
    const float* x_seq = (const float*)d_in[0];
    const float* dt_p  = (const float*)d_in[1];
    const float* W_in  = (const float*)d_in[2];
    const float* b_in  = (const float*)d_in[3];
    const float* W_rec = (const float*)d_in[4];
    const float* b_rec = (const float*)d_in[5];
    const float* tau   = (const float*)d_in[6];
    const float* W_cls = (const float*)d_in[7];
    const float* b_cls = (const float*)d_in[8];
    const int*   ode_s = (const int*)d_in[9];
    float* outp = (float*)d_out;

    const int B = in_sizes[0] / (T_LEN * F_DIM);  // 4096
    const int grid = (B + BPW - 1) / BPW;         // 256 blocks x 4 waves

    liquid_rnn_f16<<<grid, 256, 0, stream>>>(x_seq, dt_p, W_in, b_in, W_rec, b_rec,
                                             tau, W_cls, b_cls, ode_s, outp, B);
}